// Round 1
// baseline (1372.779 us; speedup 1.0000x reference)
//
#include <hip/hip_runtime.h>
#include <hip/hip_bf16.h>

typedef short bf16x8 __attribute__((ext_vector_type(8)));   // 8 bf16 bit-patterns (4 VGPR)
typedef float f32x4 __attribute__((ext_vector_type(4)));

__device__ inline short f2bf(float f) {
    __bf16 h = (__bf16)f;
    return __builtin_bit_cast(short, h);
}

__device__ inline void gload_lds16(const void* g, void* l) {
    __builtin_amdgcn_global_load_lds(
        (const __attribute__((address_space(1))) void*)g,
        (__attribute__((address_space(3))) void*)l, 16, 0, 0);
}

// ---------------- LayerNorm (fp32 in -> bf16 out) ----------------
// one block (256 thr) per token row of 2048
__global__ __launch_bounds__(256) void ln_kernel(const float* __restrict__ x,
                                                 const float* __restrict__ sc,
                                                 const float* __restrict__ bs,
                                                 short* __restrict__ o) {
    __shared__ float red[8];
    const int row = blockIdx.x;
    const int t = threadIdx.x;
    const float* xr = x + (size_t)row * 2048 + t * 8;
    float4 a = *(const float4*)xr;
    float4 b = *(const float4*)(xr + 4);
    float v[8] = {a.x, a.y, a.z, a.w, b.x, b.y, b.z, b.w};
    float s = 0.f, q = 0.f;
#pragma unroll
    for (int j = 0; j < 8; ++j) { s += v[j]; q += v[j] * v[j]; }
#pragma unroll
    for (int off = 32; off; off >>= 1) {
        s += __shfl_down(s, off, 64);
        q += __shfl_down(q, off, 64);
    }
    const int wv = t >> 6, ln = t & 63;
    if (ln == 0) { red[wv] = s; red[4 + wv] = q; }
    __syncthreads();
    s = red[0] + red[1] + red[2] + red[3];
    q = red[4] + red[5] + red[6] + red[7];
    const float mu = s * (1.f / 2048.f);
    const float var = q * (1.f / 2048.f) - mu * mu;
    const float rstd = rsqrtf(var + 1e-6f);
    const float* scp = sc + t * 8;
    const float* bp = bs + t * 8;
    bf16x8 ov;
#pragma unroll
    for (int j = 0; j < 8; ++j) ov[j] = f2bf((v[j] - mu) * rstd * scp[j] + bp[j]);
    *(bf16x8*)(o + (size_t)row * 2048 + t * 8) = ov;
}

// ---------------- transpose + fp32->bf16 convert ----------------
// src [R][C] f32 row-major  ->  dst [C][R] bf16 row-major
__global__ __launch_bounds__(256) void transpose_conv(const float* __restrict__ src,
                                                      short* __restrict__ dst,
                                                      int R, int C) {
    __shared__ float tile[32][33];
    const int tc = blockIdx.x, tr = blockIdx.y;   // col-tile, row-tile of src
    const int t = threadIdx.x;
    const int c = t & 31, r8 = t >> 5;            // 8 rows per pass
#pragma unroll
    for (int rr = r8; rr < 32; rr += 8)
        tile[rr][c] = src[(size_t)(tr * 32 + rr) * C + tc * 32 + c];
    __syncthreads();
#pragma unroll
    for (int rr = r8; rr < 32; rr += 8)
        dst[(size_t)(tc * 32 + rr) * R + tr * 32 + c] = f2bf(tile[c][rr]);
}

// ---------------- GEMM1 + GEGLU epilogue ----------------
// A = ln bf16 [8192][2048], Bt = W1T bf16 [16384][2048] (row j = a*8192+f)
// act[m][f] = gelu(z0[m][f]) * z1[m][f], bf16 [8192][8192]
__global__ __launch_bounds__(256) void gemm1_geglu(const short* __restrict__ A,
                                                   const short* __restrict__ Bt,
                                                   short* __restrict__ act) {
    constexpr int K = 2048;
    constexpr int NACT = 8192;
    __shared__ short As[128 * 32];
    __shared__ short Bs[128 * 32];
    const int t = threadIdx.x;
    const int lane = t & 63;
    const int wv = t >> 6;
    const int wr = wv >> 1, wc = wv & 1;
    const int lr = lane & 15, lg = lane >> 4;
    const int m0 = blockIdx.y * 128;
    const int c0 = blockIdx.x * 64;

    const int srow = t >> 2;                 // 0..63
    const int scol = (t & 3) * 8;            // k elems
    const size_t a_b0 = (size_t)(m0 + srow) * K + scol;
    const size_t a_b1 = (size_t)(m0 + 64 + srow) * K + scol;
    const size_t b_b0 = (size_t)(c0 + srow) * K + scol;          // z0 rows (gelu slice)
    const size_t b_b1 = (size_t)(8192 + c0 + srow) * K + scol;   // z1 rows (linear slice)
    char* asl = (char*)As + t * 16;
    char* bsl = (char*)Bs + t * 16;

    f32x4 acc0[4][2] = {};
    f32x4 acc1[4][2] = {};

    for (int k0 = 0; k0 < K; k0 += 32) {
        __syncthreads();
        gload_lds16(A + a_b0 + k0, asl);
        gload_lds16(A + a_b1 + k0, asl + 4096);
        gload_lds16(Bt + b_b0 + k0, bsl);
        gload_lds16(Bt + b_b1 + k0, bsl + 4096);
        __syncthreads();
        bf16x8 af[4];
#pragma unroll
        for (int m = 0; m < 4; ++m)
            af[m] = *(const bf16x8*)(As + (wr * 64 + m * 16 + lr) * 32 + lg * 8);
        bf16x8 b0[2], b1[2];
#pragma unroll
        for (int n = 0; n < 2; ++n) {
            b0[n] = *(const bf16x8*)(Bs + (wc * 32 + n * 16 + lr) * 32 + lg * 8);
            b1[n] = *(const bf16x8*)(Bs + (64 + wc * 32 + n * 16 + lr) * 32 + lg * 8);
        }
#pragma unroll
        for (int m = 0; m < 4; ++m)
#pragma unroll
            for (int n = 0; n < 2; ++n) {
                acc0[m][n] = __builtin_amdgcn_mfma_f32_16x16x32_bf16(af[m], b0[n], acc0[m][n], 0, 0, 0);
                acc1[m][n] = __builtin_amdgcn_mfma_f32_16x16x32_bf16(af[m], b1[n], acc1[m][n], 0, 0, 0);
            }
    }
#pragma unroll
    for (int m = 0; m < 4; ++m)
#pragma unroll
        for (int n = 0; n < 2; ++n) {
            f32x4 g = acc0[m][n], li = acc1[m][n];
            const int col = c0 + wc * 32 + n * 16 + lr;
            const int rowb = m0 + wr * 64 + m * 16 + lg * 4;
#pragma unroll
            for (int r = 0; r < 4; ++r) {
                float z0 = g[r];
                float ge = 0.5f * z0 * (1.f + tanhf(0.7978845608028654f * (z0 + 0.044715f * z0 * z0 * z0)));
                act[(size_t)(rowb + r) * NACT + col] = f2bf(ge * li[r]);
            }
        }
}

// ---------------- GEMM2 ----------------
// A = act bf16 [8192][8192], Bt = W2T bf16 [2048][8192] -> out fp32 [8192][2048]
__global__ __launch_bounds__(256) void gemm2(const short* __restrict__ A,
                                             const short* __restrict__ Bt,
                                             float* __restrict__ out) {
    constexpr int K = 8192;
    constexpr int N = 2048;
    __shared__ short As[128 * 32];
    __shared__ short Bs[128 * 32];
    const int t = threadIdx.x;
    const int lane = t & 63;
    const int wv = t >> 6;
    const int wr = wv >> 1, wc = wv & 1;
    const int lr = lane & 15, lg = lane >> 4;
    const int m0 = blockIdx.y * 128;
    const int n0 = blockIdx.x * 128;

    const int srow = t >> 2;
    const int scol = (t & 3) * 8;
    const size_t a_b0 = (size_t)(m0 + srow) * K + scol;
    const size_t a_b1 = (size_t)(m0 + 64 + srow) * K + scol;
    const size_t b_b0 = (size_t)(n0 + srow) * K + scol;
    const size_t b_b1 = (size_t)(n0 + 64 + srow) * K + scol;
    char* asl = (char*)As + t * 16;
    char* bsl = (char*)Bs + t * 16;

    f32x4 acc[4][4] = {};

    for (int k0 = 0; k0 < K; k0 += 32) {
        __syncthreads();
        gload_lds16(A + a_b0 + k0, asl);
        gload_lds16(A + a_b1 + k0, asl + 4096);
        gload_lds16(Bt + b_b0 + k0, bsl);
        gload_lds16(Bt + b_b1 + k0, bsl + 4096);
        __syncthreads();
        bf16x8 af[4], bf[4];
#pragma unroll
        for (int m = 0; m < 4; ++m)
            af[m] = *(const bf16x8*)(As + (wr * 64 + m * 16 + lr) * 32 + lg * 8);
#pragma unroll
        for (int n = 0; n < 4; ++n)
            bf[n] = *(const bf16x8*)(Bs + (wc * 64 + n * 16 + lr) * 32 + lg * 8);
#pragma unroll
        for (int m = 0; m < 4; ++m)
#pragma unroll
            for (int n = 0; n < 4; ++n)
                acc[m][n] = __builtin_amdgcn_mfma_f32_16x16x32_bf16(af[m], bf[n], acc[m][n], 0, 0, 0);
    }
#pragma unroll
    for (int m = 0; m < 4; ++m)
#pragma unroll
        for (int n = 0; n < 4; ++n) {
            const int col = n0 + wc * 64 + n * 16 + lr;
            const int rowb = m0 + wr * 64 + m * 16 + lg * 4;
#pragma unroll
            for (int r = 0; r < 4; ++r)
                out[(size_t)(rowb + r) * N + col] = acc[m][n][r];
        }
}

extern "C" void kernel_launch(void* const* d_in, const int* in_sizes, int n_in,
                              void* d_out, int out_size, void* d_ws, size_t ws_size,
                              hipStream_t stream) {
    const float* x = (const float*)d_in[0];      // [2048,4,2048]
    const float* scale = (const float*)d_in[1];  // [2048]
    const float* lnb = (const float*)d_in[2];    // [2048]
    const float* w1 = (const float*)d_in[3];     // [2048,2,8192]
    const float* w2 = (const float*)d_in[4];     // [8192,2048]
    float* out = (float*)d_out;

    // ws layout (bf16): ln[8192*2048] | w1t[16384*2048] | w2t[2048*8192] | act[8192*8192]
    const size_t NEED = 268435456;  // 256 MB
    if (ws_size < NEED) return;     // leaves d_out poisoned -> visible failure signal
    char* ws = (char*)d_ws;
    short* lnq = (short*)ws;                       // 32 MB
    short* w1t = (short*)(ws + 33554432ull);       // 64 MB
    short* w2t = (short*)(ws + 100663296ull);      // 32 MB
    short* act = (short*)(ws + 134217728ull);      // 128 MB

    ln_kernel<<<8192, 256, 0, stream>>>(x, scale, lnb, lnq);
    transpose_conv<<<dim3(512, 64), 256, 0, stream>>>(w1, w1t, 2048, 16384);
    transpose_conv<<<dim3(64, 256), 256, 0, stream>>>(w2, w2t, 8192, 2048);
    gemm1_geglu<<<dim3(128, 64), 256, 0, stream>>>(lnq, w1t, act);
    gemm2<<<dim3(16, 64), 256, 0, stream>>>(act, w2t, out);
}

// Round 3
// 1281.639 us; speedup vs baseline: 1.0711x; 1.0711x over previous
//
#include <hip/hip_runtime.h>
#include <hip/hip_bf16.h>

typedef short bf16x8 __attribute__((ext_vector_type(8)));   // 8 bf16 bit-patterns (4 VGPR)
typedef float f32x4 __attribute__((ext_vector_type(4)));

__device__ inline short f2bf(float f) {
    __bf16 h = (__bf16)f;
    return __builtin_bit_cast(short, h);
}

__device__ inline void gload_lds16(const void* g, void* l) {
    __builtin_amdgcn_global_load_lds(
        (const __attribute__((address_space(1))) void*)g,
        (__attribute__((address_space(3))) void*)l, 16, 0, 0);
}

#define VMCNT(n) asm volatile("s_waitcnt vmcnt(" #n ")" ::: "memory")
#define LGK0     asm volatile("s_waitcnt lgkmcnt(0)" ::: "memory")

// ---------------- LayerNorm (fp32 in -> bf16 out) ----------------
__global__ __launch_bounds__(256) void ln_kernel(const float* __restrict__ x,
                                                 const float* __restrict__ sc,
                                                 const float* __restrict__ bs,
                                                 short* __restrict__ o) {
    __shared__ float red[8];
    const int row = blockIdx.x;
    const int t = threadIdx.x;
    const float* xr = x + (size_t)row * 2048 + t * 8;
    float4 a = *(const float4*)xr;
    float4 b = *(const float4*)(xr + 4);
    float v[8] = {a.x, a.y, a.z, a.w, b.x, b.y, b.z, b.w};
    float s = 0.f, q = 0.f;
#pragma unroll
    for (int j = 0; j < 8; ++j) { s += v[j]; q += v[j] * v[j]; }
#pragma unroll
    for (int off = 32; off; off >>= 1) {
        s += __shfl_down(s, off, 64);
        q += __shfl_down(q, off, 64);
    }
    const int wv = t >> 6, ln = t & 63;
    if (ln == 0) { red[wv] = s; red[4 + wv] = q; }
    __syncthreads();
    s = red[0] + red[1] + red[2] + red[3];
    q = red[4] + red[5] + red[6] + red[7];
    const float mu = s * (1.f / 2048.f);
    const float var = q * (1.f / 2048.f) - mu * mu;
    const float rstd = rsqrtf(var + 1e-6f);
    const float* scp = sc + t * 8;
    const float* bp = bs + t * 8;
    bf16x8 ov;
#pragma unroll
    for (int j = 0; j < 8; ++j) ov[j] = f2bf((v[j] - mu) * rstd * scp[j] + bp[j]);
    *(bf16x8*)(o + (size_t)row * 2048 + t * 8) = ov;
}

// ---------------- generic transpose + fp32->bf16 (for W2) ----------------
// src [R][C] f32 row-major  ->  dst [C][R] bf16 row-major
__global__ __launch_bounds__(256) void transpose_conv(const float* __restrict__ src,
                                                      short* __restrict__ dst,
                                                      int R, int C) {
    __shared__ float tile[32][33];
    const int tc = blockIdx.x, tr = blockIdx.y;
    const int t = threadIdx.x;
    const int c = t & 31, r8 = t >> 5;
#pragma unroll
    for (int rr = r8; rr < 32; rr += 8)
        tile[rr][c] = src[(size_t)(tr * 32 + rr) * C + tc * 32 + c];
    __syncthreads();
#pragma unroll
    for (int rr = r8; rr < 32; rr += 8)
        dst[(size_t)(tc * 32 + rr) * R + tr * 32 + c] = f2bf(tile[c][rr]);
}

// ---------------- W1 transpose with z0/z1 16-col interleave ----------------
// src W1 [2048][2][8192] f32.  dst row j = (f>>4)*32 + a*16 + (f&15), col k.
// So a 32-row group of dst = {z0 f16cols, z1 same f16cols} -> GEGLU pairs land
// in the same lane of the same wave in gemm1.
__global__ __launch_bounds__(256) void transpose_w1(const float* __restrict__ src,
                                                    short* __restrict__ dst) {
    __shared__ float tile[32][33];
    const int f0 = blockIdx.x * 32;
    const int k0 = blockIdx.y * 32;
    const int a = blockIdx.z;
    const int t = threadIdx.x;
    const int c = t & 31, r8 = t >> 5;
#pragma unroll
    for (int rr = r8; rr < 32; rr += 8)
        tile[rr][c] = src[(size_t)(k0 + rr) * 16384 + a * 8192 + f0 + c];  // [k][f]
    __syncthreads();
#pragma unroll
    for (int rr = r8; rr < 32; rr += 8) {
        const int j = f0 * 2 + (rr & 16) * 2 + a * 16 + (rr & 15);
        dst[(size_t)j * 2048 + k0 + c] = f2bf(tile[c][rr]);
    }
}

// ---------------- 256x256-tile 8-phase GEMM core ----------------
// A [M][K], B [N][K] row-major bf16. 512 thr = 8 waves (2M x 4N), wave out 128x64.
// LDS: 4-slot ring of 32KB chunks; chunk c = k-range [c*32, c*32+32) of BOTH
// A-tile (256 rows, 16KB) and B-tile (256 rows, 16KB). Rows are 64B -> b128
// fragment reads are bank-conflict-free without swizzle, and global_load_lds
// destinations stay linear (rule #21).
// Schedule per K-tile t (chunks 2t, 2t+1): P1(c0,mh0,issue 2t+3) P2(c0,mh1)
// P3(c1,mh0,issue 2t+4) P4(c1,mh1,vmcnt(4)).  vmcnt never drains to 0.
template <int K, int NT>
__device__ inline void gemm_core(const short* __restrict__ A, const short* __restrict__ B,
                                 int m0, int n0, char* lds, f32x4 (&acc)[8][4]) {
    const int tid = threadIdx.x;
    const int lane = tid & 63;
    const int wid = tid >> 6;
    const int wr = wid >> 2, wc = wid & 3;
    const int lr = lane & 15, lg = lane >> 4;

    const short* gA = A + (size_t)(m0 + (tid >> 2)) * K + (tid & 3) * 8;
    const short* gB = B + (size_t)(n0 + (tid >> 2)) * K + (tid & 3) * 8;
    char* dA = lds + tid * 16;
    char* dB = lds + 16384 + tid * 16;

    auto issue = [&](int c) {
        const int cc = c < 2 * NT - 1 ? c : 2 * NT - 1;
        const int so = (cc & 3) * 32768;
        const size_t ko = (size_t)cc * 32;
        gload_lds16(gA + ko, dA + so);
        gload_lds16(gA + (size_t)128 * K + ko, dA + so + 8192);
        gload_lds16(gB + ko, dB + so);
        gload_lds16(gB + (size_t)128 * K + ko, dB + so + 8192);
    };

    const int rdA = (wr * 128 + lr) * 64 + lg * 16;
    const int rdB = 16384 + (wc * 64 + lr) * 64 + lg * 16;

    issue(0); issue(1); issue(2);
    VMCNT(4);
    __builtin_amdgcn_s_barrier();

    bf16x8 aF[4], bF[4];

#define PHASE(SB, MH, PRE_ISSUE, PRE_BAR2)                                          \
    {                                                                               \
        if ((MH) == 0) {                                                            \
            _Pragma("unroll") for (int n = 0; n < 4; ++n)                           \
                bF[n] = *(const bf16x8*)(lds + (SB) + rdB + n * 1024);              \
        }                                                                           \
        _Pragma("unroll") for (int m = 0; m < 4; ++m)                               \
            aF[m] = *(const bf16x8*)(lds + (SB) + rdA + ((MH)*4 + m) * 1024);       \
        PRE_ISSUE;                                                                  \
        __builtin_amdgcn_s_barrier();                                               \
        LGK0;                                                                       \
        __builtin_amdgcn_s_setprio(1);                                              \
        _Pragma("unroll") for (int m = 0; m < 4; ++m) {                             \
            _Pragma("unroll") for (int n = 0; n < 4; ++n)                           \
                acc[(MH)*4 + m][n] = __builtin_amdgcn_mfma_f32_16x16x32_bf16(       \
                    aF[m], bF[n], acc[(MH)*4 + m][n], 0, 0, 0);                     \
        }                                                                           \
        __builtin_amdgcn_s_setprio(0);                                              \
        PRE_BAR2;                                                                   \
        __builtin_amdgcn_s_barrier();                                               \
    }

#pragma unroll 1
    for (int tt = 0; tt < NT / 2; ++tt) {
        const int c0 = 4 * tt;
        PHASE(0,     0, issue(c0 + 3), (void)0);
        PHASE(0,     1, (void)0,       (void)0);
        PHASE(32768, 0, issue(c0 + 4), (void)0);
        PHASE(32768, 1, (void)0,       VMCNT(4));
        PHASE(65536, 0, issue(c0 + 5), (void)0);
        PHASE(65536, 1, (void)0,       (void)0);
        PHASE(98304, 0, issue(c0 + 6), (void)0);
        PHASE(98304, 1, (void)0,       VMCNT(4));
    }
#undef PHASE
}

__device__ inline float gelu_tanh(float z) {
    const float u = 0.7978845608028654f * (z + 0.044715f * z * z * z);
    const float e = __expf(fminf(2.f * u, 80.f));
    return 0.5f * z * (1.f + (e - 1.f) / (e + 1.f));
}

// ---------------- GEMM1 + fused GEGLU ----------------
// A = lnq [8192][2048], B = w1t [16384][2048] (interleaved z0/z1 rows).
// Output act bf16 [8192][8192].
__global__ __launch_bounds__(512, 2) void gemm1_geglu(const short* __restrict__ A,
                                                      const short* __restrict__ Bt,
                                                      short* __restrict__ act) {
    extern __shared__ char lds[];
    const int bid = blockIdx.x;                  // 2048 blocks
    const int sid = (bid & 7) * 256 + (bid >> 3);  // XCD swizzle (2048 % 8 == 0)
    const int mb = sid & 31, nb = sid >> 5;

    f32x4 acc[8][4] = {};
    gemm_core<2048, 32>(A, Bt, mb * 256, nb * 256, lds, acc);

    const int tid = threadIdx.x;
    const int lane = tid & 63;
    const int wid = tid >> 6;
    const int wr = wid >> 2, wc = wid & 3;
    const int lr = lane & 15, lg = lane >> 4;
#pragma unroll
    for (int m = 0; m < 8; ++m) {
#pragma unroll
        for (int p = 0; p < 2; ++p) {
            const f32x4 g = acc[m][2 * p];       // a=0 slice (gelu)
            const f32x4 li = acc[m][2 * p + 1];  // a=1 slice (linear)
            const int col = nb * 128 + wc * 32 + p * 16 + lr;
            const int row0 = mb * 256 + wr * 128 + m * 16 + lg * 4;
#pragma unroll
            for (int r = 0; r < 4; ++r)
                act[(size_t)(row0 + r) * 8192 + col] = f2bf(gelu_tanh(g[r]) * li[r]);
        }
    }
}

// ---------------- GEMM2 ----------------
// A = act [8192][8192], B = w2t [2048][8192] -> out fp32 [8192][2048]
__global__ __launch_bounds__(512, 2) void gemm2(const short* __restrict__ A,
                                                const short* __restrict__ Bt,
                                                float* __restrict__ out) {
    extern __shared__ char lds[];
    const int bid = blockIdx.x;                 // 256 blocks
    const int sid = (bid & 7) * 32 + (bid >> 3);  // XCD swizzle (256 % 8 == 0)
    const int mb = sid & 31, nb = sid >> 5;     // nb in 0..7

    f32x4 acc[8][4] = {};
    gemm_core<8192, 128>(A, Bt, mb * 256, nb * 256, lds, acc);

    const int tid = threadIdx.x;
    const int lane = tid & 63;
    const int wid = tid >> 6;
    const int wr = wid >> 2, wc = wid & 3;
    const int lr = lane & 15, lg = lane >> 4;
#pragma unroll
    for (int m = 0; m < 8; ++m) {
#pragma unroll
        for (int n = 0; n < 4; ++n) {
            const int col = nb * 256 + wc * 64 + n * 16 + lr;
            const int row0 = mb * 256 + wr * 128 + m * 16 + lg * 4;
#pragma unroll
            for (int r = 0; r < 4; ++r)
                out[(size_t)(row0 + r) * 2048 + col] = acc[m][n][r];
        }
    }
}

extern "C" void kernel_launch(void* const* d_in, const int* in_sizes, int n_in,
                              void* d_out, int out_size, void* d_ws, size_t ws_size,
                              hipStream_t stream) {
    const float* x = (const float*)d_in[0];      // [2048,4,2048]
    const float* scale = (const float*)d_in[1];  // [2048]
    const float* lnb = (const float*)d_in[2];    // [2048]
    const float* w1 = (const float*)d_in[3];     // [2048,2,8192]
    const float* w2 = (const float*)d_in[4];     // [8192,2048]
    float* out = (float*)d_out;

    // ws layout (bf16): ln[8192*2048] | w1t[16384*2048] | w2t[2048*8192] | act[8192*8192]
    const size_t NEED = 268435456;  // 256 MB
    if (ws_size < NEED) return;
    char* ws = (char*)d_ws;
    short* lnq = (short*)ws;                     // 32 MB
    short* w1t = (short*)(ws + 33554432ull);     // 64 MB
    short* w2t = (short*)(ws + 100663296ull);    // 32 MB
    short* act = (short*)(ws + 134217728ull);    // 128 MB

    ln_kernel<<<8192, 256, 0, stream>>>(x, scale, lnb, lnq);
    transpose_w1<<<dim3(256, 64, 2), 256, 0, stream>>>(w1, w1t);
    transpose_conv<<<dim3(64, 256), 256, 0, stream>>>(w2, w2t, 8192, 2048);
    gemm1_geglu<<<2048, 512, 131072, stream>>>(lnq, w1t, act);
    gemm2<<<256, 512, 131072, stream>>>(act, w2t, out);
}

// Round 4
// 1252.645 us; speedup vs baseline: 1.0959x; 1.0231x over previous
//
#include <hip/hip_runtime.h>
#include <hip/hip_bf16.h>

typedef short bf16x8 __attribute__((ext_vector_type(8)));   // 8 bf16 bit-patterns (4 VGPR)
typedef float f32x4 __attribute__((ext_vector_type(4)));

__device__ inline short f2bf(float f) {
    __bf16 h = (__bf16)f;
    return __builtin_bit_cast(short, h);
}

__device__ inline void gload_lds16(const void* g, void* l) {
    __builtin_amdgcn_global_load_lds(
        (const __attribute__((address_space(1))) void*)g,
        (__attribute__((address_space(3))) void*)l, 16, 0, 0);
}

#define VMCNT(n) asm volatile("s_waitcnt vmcnt(" #n ")" ::: "memory")
#define LGK0     asm volatile("s_waitcnt lgkmcnt(0)" ::: "memory")

// ---------------- LayerNorm (fp32 in -> bf16 out) ----------------
__global__ __launch_bounds__(256) void ln_kernel(const float* __restrict__ x,
                                                 const float* __restrict__ sc,
                                                 const float* __restrict__ bs,
                                                 short* __restrict__ o) {
    __shared__ float red[8];
    const int row = blockIdx.x;
    const int t = threadIdx.x;
    const float* xr = x + (size_t)row * 2048 + t * 8;
    float4 a = *(const float4*)xr;
    float4 b = *(const float4*)(xr + 4);
    float v[8] = {a.x, a.y, a.z, a.w, b.x, b.y, b.z, b.w};
    float s = 0.f, q = 0.f;
#pragma unroll
    for (int j = 0; j < 8; ++j) { s += v[j]; q += v[j] * v[j]; }
#pragma unroll
    for (int off = 32; off; off >>= 1) {
        s += __shfl_down(s, off, 64);
        q += __shfl_down(q, off, 64);
    }
    const int wv = t >> 6, ln = t & 63;
    if (ln == 0) { red[wv] = s; red[4 + wv] = q; }
    __syncthreads();
    s = red[0] + red[1] + red[2] + red[3];
    q = red[4] + red[5] + red[6] + red[7];
    const float mu = s * (1.f / 2048.f);
    const float var = q * (1.f / 2048.f) - mu * mu;
    const float rstd = rsqrtf(var + 1e-6f);
    const float* scp = sc + t * 8;
    const float* bp = bs + t * 8;
    bf16x8 ov;
#pragma unroll
    for (int j = 0; j < 8; ++j) ov[j] = f2bf((v[j] - mu) * rstd * scp[j] + bp[j]);
    *(bf16x8*)(o + (size_t)row * 2048 + t * 8) = ov;
}

// ---------------- generic transpose + fp32->bf16 (for W2) ----------------
// src [R][C] f32 row-major  ->  dst [C][R] bf16 row-major
__global__ __launch_bounds__(256) void transpose_conv(const float* __restrict__ src,
                                                      short* __restrict__ dst,
                                                      int R, int C) {
    __shared__ float tile[32][33];
    const int tc = blockIdx.x, tr = blockIdx.y;
    const int t = threadIdx.x;
    const int c = t & 31, r8 = t >> 5;
#pragma unroll
    for (int rr = r8; rr < 32; rr += 8)
        tile[rr][c] = src[(size_t)(tr * 32 + rr) * C + tc * 32 + c];
    __syncthreads();
#pragma unroll
    for (int rr = r8; rr < 32; rr += 8)
        dst[(size_t)(tc * 32 + rr) * R + tr * 32 + c] = f2bf(tile[c][rr]);
}

// ---------------- W1 transpose with z0/z1 16-col interleave ----------------
// src W1 [2048][2][8192] f32.  dst row j = (f>>4)*32 + a*16 + (f&15), col k.
// So a 32-row group of dst = {z0 f16cols, z1 same f16cols} -> GEGLU pairs land
// in the same lane of the same wave in gemm1.
__global__ __launch_bounds__(256) void transpose_w1(const float* __restrict__ src,
                                                    short* __restrict__ dst) {
    __shared__ float tile[32][33];
    const int f0 = blockIdx.x * 32;
    const int k0 = blockIdx.y * 32;
    const int a = blockIdx.z;
    const int t = threadIdx.x;
    const int c = t & 31, r8 = t >> 5;
#pragma unroll
    for (int rr = r8; rr < 32; rr += 8)
        tile[rr][c] = src[(size_t)(k0 + rr) * 16384 + a * 8192 + f0 + c];  // [k][f]
    __syncthreads();
#pragma unroll
    for (int rr = r8; rr < 32; rr += 8) {
        const int j = f0 * 2 + (rr & 16) * 2 + a * 16 + (rr & 15);
        dst[(size_t)j * 2048 + k0 + c] = f2bf(tile[c][rr]);
    }
}

// ---------------- 256x256-tile 8-phase GEMM core (T2-swizzled LDS) ----------------
// A [M][K], B [N][K] row-major bf16. 512 thr = 8 waves (2M x 4N), wave out 128x64.
// LDS: 4-slot ring of 32KB chunks; chunk c = k-range [c*32, c*32+32) of BOTH
// A-tile (256 rows x 64B) and B-tile (256 rows x 64B).
// T2 swizzle: view each 128B row-PAIR as 8 x 16B granules s8 = (row&1)*4 + lg;
// stored granule s8' = s8 ^ ((row>>1)&7).  LDS dest of global_load_lds stays
// LINEAR (rule #21): the inverse perm is applied to each thread's GLOBAL source
// (row_src/col_src below), and the same XOR is applied to fragment-read offsets.
// Quarter-wave b128 reads then hit each 4-bank group exactly 2x (free, m136).
// Schedule per K-tile t (chunks 2t,2t+1): P1(c0,mh0,issue 2t+3) P2(c0,mh1)
// P3(c1,mh0,issue 2t+4) P4(c1,mh1,vmcnt(4)).  vmcnt never drains to 0.
template <int K, int NT>
__device__ inline void gemm_core(const short* __restrict__ A, const short* __restrict__ B,
                                 int m0, int n0, char* lds, f32x4 (&acc)[8][4]) {
    const int tid = threadIdx.x;
    const int lane = tid & 63;
    const int wid = tid >> 6;
    const int wr = wid >> 2, wc = wid & 3;
    const int lr = lane & 15, lg = lane >> 4;

    // staging: thread t's linear LDS dest granule = (R = t>>3, s8 = t&7);
    // fetch the global granule that belongs there: s8_src = s8 ^ (R&7)
    const int sw = (tid & 7) ^ ((tid >> 3) & 7);
    const int row_src = ((tid >> 3) << 1) + (sw >> 2);   // 0..127
    const int col_src = (sw & 3) * 8;                    // element offset in 32-elem chunk
    const short* gA = A + (size_t)(m0 + row_src) * K + col_src;
    const short* gB = B + (size_t)(n0 + row_src) * K + col_src;
    char* dA = lds + tid * 16;
    char* dB = lds + 16384 + tid * 16;

    auto issue = [&](int c) {
        const int cc = c < 2 * NT - 1 ? c : 2 * NT - 1;
        const int so = (cc & 3) * 32768;
        const size_t ko = (size_t)cc * 32;
        gload_lds16(gA + ko, dA + so);
        gload_lds16(gA + (size_t)128 * K + ko, dA + so + 8192);
        gload_lds16(gB + ko, dB + so);
        gload_lds16(gB + (size_t)128 * K + ko, dB + so + 8192);
    };

    // fragment read offset with matching swizzle:
    // row = base16 + lr, addr = (row>>1)*128 + ((((row&1)*4)|lg) ^ ((row>>1)&7))*16
    const int laneoff = ((lr >> 1) << 7) |
                        ((((((lane & 1) << 2) | lg)) ^ ((lr >> 1) & 7)) << 4);
    const int rdA = wr * 8192 + laneoff;
    const int rdB = 16384 + wc * 4096 + laneoff;

    issue(0); issue(1); issue(2);
    VMCNT(4);
    __builtin_amdgcn_s_barrier();

    bf16x8 aF[4], bF[4];

#define PHASE(SB, MH, PRE_ISSUE, PRE_BAR2)                                          \
    {                                                                               \
        if ((MH) == 0) {                                                            \
            _Pragma("unroll") for (int n = 0; n < 4; ++n)                           \
                bF[n] = *(const bf16x8*)(lds + (SB) + rdB + n * 1024);              \
        }                                                                           \
        _Pragma("unroll") for (int m = 0; m < 4; ++m)                               \
            aF[m] = *(const bf16x8*)(lds + (SB) + rdA + ((MH)*4 + m) * 1024);       \
        PRE_ISSUE;                                                                  \
        __builtin_amdgcn_s_barrier();                                               \
        LGK0;                                                                       \
        __builtin_amdgcn_s_setprio(1);                                              \
        _Pragma("unroll") for (int m = 0; m < 4; ++m) {                             \
            _Pragma("unroll") for (int n = 0; n < 4; ++n)                           \
                acc[(MH)*4 + m][n] = __builtin_amdgcn_mfma_f32_16x16x32_bf16(       \
                    aF[m], bF[n], acc[(MH)*4 + m][n], 0, 0, 0);                     \
        }                                                                           \
        __builtin_amdgcn_s_setprio(0);                                              \
        PRE_BAR2;                                                                   \
        __builtin_amdgcn_s_barrier();                                               \
    }

#pragma unroll 1
    for (int tt = 0; tt < NT / 2; ++tt) {
        const int c0 = 4 * tt;
        PHASE(0,     0, issue(c0 + 3), (void)0);
        PHASE(0,     1, (void)0,       (void)0);
        PHASE(32768, 0, issue(c0 + 4), (void)0);
        PHASE(32768, 1, (void)0,       VMCNT(4));
        PHASE(65536, 0, issue(c0 + 5), (void)0);
        PHASE(65536, 1, (void)0,       (void)0);
        PHASE(98304, 0, issue(c0 + 6), (void)0);
        PHASE(98304, 1, (void)0,       VMCNT(4));
    }
#undef PHASE
}

__device__ inline float gelu_tanh(float z) {
    const float u = 0.7978845608028654f * (z + 0.044715f * z * z * z);
    const float e = __expf(fminf(2.f * u, 80.f));
    return 0.5f * z * (1.f + (e - 1.f) / (e + 1.f));
}

// ---------------- GEMM1 + fused GEGLU ----------------
// A = lnq [8192][2048], B = w1t [16384][2048] (interleaved z0/z1 rows).
// Output act bf16 [8192][8192].
__global__ __launch_bounds__(512, 2) void gemm1_geglu(const short* __restrict__ A,
                                                      const short* __restrict__ Bt,
                                                      short* __restrict__ act) {
    extern __shared__ char lds[];
    const int bid = blockIdx.x;                  // 2048 blocks
    const int sid = (bid & 7) * 256 + (bid >> 3);  // XCD swizzle (2048 % 8 == 0)
    const int mb = sid & 31, nb = sid >> 5;

    f32x4 acc[8][4] = {};
    gemm_core<2048, 32>(A, Bt, mb * 256, nb * 256, lds, acc);

    const int tid = threadIdx.x;
    const int lane = tid & 63;
    const int wid = tid >> 6;
    const int wr = wid >> 2, wc = wid & 3;
    const int lr = lane & 15, lg = lane >> 4;
#pragma unroll
    for (int m = 0; m < 8; ++m) {
#pragma unroll
        for (int p = 0; p < 2; ++p) {
            const f32x4 g = acc[m][2 * p];       // a=0 slice (gelu)
            const f32x4 li = acc[m][2 * p + 1];  // a=1 slice (linear)
            const int col = nb * 128 + wc * 32 + p * 16 + lr;
            const int row0 = mb * 256 + wr * 128 + m * 16 + lg * 4;
#pragma unroll
            for (int r = 0; r < 4; ++r)
                act[(size_t)(row0 + r) * 8192 + col] = f2bf(gelu_tanh(g[r]) * li[r]);
        }
    }
}

// ---------------- GEMM2 ----------------
// A = act [8192][8192], B = w2t [2048][8192] -> out fp32 [8192][2048]
__global__ __launch_bounds__(512, 2) void gemm2(const short* __restrict__ A,
                                                const short* __restrict__ Bt,
                                                float* __restrict__ out) {
    extern __shared__ char lds[];
    const int bid = blockIdx.x;                 // 256 blocks
    const int sid = (bid & 7) * 32 + (bid >> 3);  // XCD swizzle (256 % 8 == 0)
    const int mb = sid & 31, nb = sid >> 5;     // nb in 0..7

    f32x4 acc[8][4] = {};
    gemm_core<8192, 128>(A, Bt, mb * 256, nb * 256, lds, acc);

    const int tid = threadIdx.x;
    const int lane = tid & 63;
    const int wid = tid >> 6;
    const int wr = wid >> 2, wc = wid & 3;
    const int lr = lane & 15, lg = lane >> 4;
#pragma unroll
    for (int m = 0; m < 8; ++m) {
#pragma unroll
        for (int n = 0; n < 4; ++n) {
            const int col = nb * 256 + wc * 64 + n * 16 + lr;
            const int row0 = mb * 256 + wr * 128 + m * 16 + lg * 4;
#pragma unroll
            for (int r = 0; r < 4; ++r)
                out[(size_t)(row0 + r) * 2048 + col] = acc[m][n][r];
        }
    }
}

extern "C" void kernel_launch(void* const* d_in, const int* in_sizes, int n_in,
                              void* d_out, int out_size, void* d_ws, size_t ws_size,
                              hipStream_t stream) {
    const float* x = (const float*)d_in[0];      // [2048,4,2048]
    const float* scale = (const float*)d_in[1];  // [2048]
    const float* lnb = (const float*)d_in[2];    // [2048]
    const float* w1 = (const float*)d_in[3];     // [2048,2,8192]
    const float* w2 = (const float*)d_in[4];     // [8192,2048]
    float* out = (float*)d_out;

    // ws layout (bf16): ln[8192*2048] | w1t[16384*2048] | w2t[2048*8192] | act[8192*8192]
    const size_t NEED = 268435456;  // 256 MB
    if (ws_size < NEED) return;
    char* ws = (char*)d_ws;
    short* lnq = (short*)ws;                     // 32 MB
    short* w1t = (short*)(ws + 33554432ull);     // 64 MB
    short* w2t = (short*)(ws + 100663296ull);    // 32 MB
    short* act = (short*)(ws + 134217728ull);    // 128 MB

    ln_kernel<<<8192, 256, 0, stream>>>(x, scale, lnb, lnq);
    transpose_w1<<<dim3(256, 64, 2), 256, 0, stream>>>(w1, w1t);
    transpose_conv<<<dim3(64, 256), 256, 0, stream>>>(w2, w2t, 8192, 2048);
    gemm1_geglu<<<2048, 512, 131072, stream>>>(lnq, w1t, act);
    gemm2<<<256, 512, 131072, stream>>>(act, w2t, out);
}